// Round 1
// baseline (100.930 us; speedup 1.0000x reference)
//
#include <hip/hip_runtime.h>

// SpatialTransformer: batched affine warp + trilinear resample.
// vol: [4,160,160,160,2] fp32, trf: [4,3,4] fp32 -> out: [4,160,160,160,2] fp32.
// Sample coord = M * (x - c) + t + c, c = (160-1)/2 = 79.5, clamped to [0,159].

constexpr int D = 160, H = 160, W = 160, C = 2;
constexpr unsigned VOX_PER_B = D * H * W;          // 4,096,000
constexpr unsigned TOTAL = 4u * VOX_PER_B;         // 16,384,000

__global__ __launch_bounds__(256) void st_affine_trilinear(
    const float* __restrict__ vol,
    const float* __restrict__ trf,
    float* __restrict__ out)
{
    unsigned tid = blockIdx.x * 256u + threadIdx.x;
    if (tid >= TOTAL) return;

    // decompose: tid -> (b, i, j, k); consecutive tid walks k (coalesced).
    unsigned k = tid % (unsigned)W;
    unsigned t = tid / (unsigned)W;
    unsigned j = t % (unsigned)H;
    t /= (unsigned)H;
    unsigned i = t % (unsigned)D;
    unsigned b = t / (unsigned)D;

    // affine row-major [3][4]; b is wave-uniform (VOX_PER_B % 64 == 0)
    const float* m = trf + b * 12u;
    float m00 = m[0], m01 = m[1], m02 = m[2],  m03 = m[3];
    float m10 = m[4], m11 = m[5], m12 = m[6],  m13 = m[7];
    float m20 = m[8], m21 = m[9], m22 = m[10], m23 = m[11];

    const float cc = 79.5f;
    float xc = (float)i - cc, yc = (float)j - cc, zc = (float)k - cc;

    float lx = fmaf(m00, xc, fmaf(m01, yc, fmaf(m02, zc, m03 + cc)));
    float ly = fmaf(m10, xc, fmaf(m11, yc, fmaf(m12, zc, m13 + cc)));
    float lz = fmaf(m20, xc, fmaf(m21, yc, fmaf(m22, zc, m23 + cc)));

    const float mx = 159.0f;
    lx = fminf(fmaxf(lx, 0.0f), mx);
    ly = fminf(fmaxf(ly, 0.0f), mx);
    lz = fminf(fmaxf(lz, 0.0f), mx);

    float fx0 = floorf(lx), fy0 = floorf(ly), fz0 = floorf(lz);
    float fx1 = fminf(fx0 + 1.0f, mx);
    float fy1 = fminf(fy0 + 1.0f, mx);
    float fz1 = fminf(fz0 + 1.0f, mx);

    int ix0 = (int)fx0, iy0 = (int)fy0, iz0 = (int)fz0;
    int ix1 = (int)fx1, iy1 = (int)fy1, iz1 = (int)fz1;

    // voxelmorph convention: w_lo = loc1 - loc (weight of LOWER corner)
    float wxl = fx1 - lx, wyl = fy1 - ly, wzl = fz1 - lz;
    float wxh = 1.0f - wxl, wyh = 1.0f - wyl, wzh = 1.0f - wzl;

    const float2* vb = (const float2*)(vol) + (size_t)b * VOX_PER_B;

    int r0 = ix0 * H, r1 = ix1 * H;
    int p00 = (r0 + iy0) * W, p01 = (r0 + iy1) * W;
    int p10 = (r1 + iy0) * W, p11 = (r1 + iy1) * W;

    float2 v000 = vb[p00 + iz0], v001 = vb[p00 + iz1];
    float2 v010 = vb[p01 + iz0], v011 = vb[p01 + iz1];
    float2 v100 = vb[p10 + iz0], v101 = vb[p10 + iz1];
    float2 v110 = vb[p11 + iz0], v111 = vb[p11 + iz1];

    float w000 = wxl * wyl * wzl, w001 = wxl * wyl * wzh;
    float w010 = wxl * wyh * wzl, w011 = wxl * wyh * wzh;
    float w100 = wxh * wyl * wzl, w101 = wxh * wyl * wzh;
    float w110 = wxh * wyh * wzl, w111 = wxh * wyh * wzh;

    float ox = v000.x * w000 + v001.x * w001 + v010.x * w010 + v011.x * w011
             + v100.x * w100 + v101.x * w101 + v110.x * w110 + v111.x * w111;
    float oy = v000.y * w000 + v001.y * w001 + v010.y * w010 + v011.y * w011
             + v100.y * w100 + v101.y * w101 + v110.y * w110 + v111.y * w111;

    float2 o; o.x = ox; o.y = oy;
    ((float2*)out)[tid] = o;
}

extern "C" void kernel_launch(void* const* d_in, const int* in_sizes, int n_in,
                              void* d_out, int out_size, void* d_ws, size_t ws_size,
                              hipStream_t stream) {
    const float* vol = (const float*)d_in[0];
    const float* trf = (const float*)d_in[1];
    float* out = (float*)d_out;

    unsigned blocks = (TOTAL + 255u) / 256u;  // 64,000 exactly
    st_affine_trilinear<<<blocks, 256, 0, stream>>>(vol, trf, out);
}

// Round 2
// 98.462 us; speedup vs baseline: 1.0251x; 1.0251x over previous
//
#include <hip/hip_runtime.h>

// SpatialTransformer: batched affine warp + trilinear resample.
// vol: [4,160,160,160,2] fp32, trf: [4,3,4] fp32 -> out: [4,160,160,160,2] fp32.
// Sample coord = M * (x - c) + t + c, c = (160-1)/2 = 79.5, clamped to [0,159].
//
// Round 2: XCD-aware bijective chunked block swizzle (T1). Blocks round-robin
// across 8 XCDs with private L2s; chunking gives each XCD a contiguous
// 80-x-plane slab so plane/row gather reuse stays within one L2.
// Measured r1: FETCH 252.7 MB vs 131 MB ideal (1.93x cross-XCD duplication).

constexpr int D = 160, H = 160, W = 160, C = 2;
constexpr unsigned VOX_PER_B = D * H * W;          // 4,096,000
constexpr unsigned TOTAL = 4u * VOX_PER_B;         // 16,384,000
constexpr unsigned NBLOCKS = TOTAL / 256u;         // 64,000 (exact)
constexpr unsigned NXCD = 8;
constexpr unsigned CHUNK = NBLOCKS / NXCD;         // 8,000

__global__ __launch_bounds__(256) void st_affine_trilinear(
    const float* __restrict__ vol,
    const float* __restrict__ trf,
    float* __restrict__ out)
{
    // bijective chunked XCD swizzle: hardware assigns blockIdx.x % 8 -> XCD;
    // remap so each XCD processes a contiguous slab of the output.
    unsigned bid = blockIdx.x;
    unsigned swz = (bid & (NXCD - 1)) * CHUNK + (bid >> 3);
    unsigned tid = swz * 256u + threadIdx.x;

    // decompose: tid -> (b, i, j, k); consecutive tid walks k (coalesced).
    unsigned k = tid % (unsigned)W;
    unsigned t = tid / (unsigned)W;
    unsigned j = t % (unsigned)H;
    t /= (unsigned)H;
    unsigned i = t % (unsigned)D;
    unsigned b = t / (unsigned)D;

    // affine row-major [3][4]; b is wave-uniform (VOX_PER_B % 64 == 0)
    const float* m = trf + b * 12u;
    float m00 = m[0], m01 = m[1], m02 = m[2],  m03 = m[3];
    float m10 = m[4], m11 = m[5], m12 = m[6],  m13 = m[7];
    float m20 = m[8], m21 = m[9], m22 = m[10], m23 = m[11];

    const float cc = 79.5f;
    float xc = (float)i - cc, yc = (float)j - cc, zc = (float)k - cc;

    float lx = fmaf(m00, xc, fmaf(m01, yc, fmaf(m02, zc, m03 + cc)));
    float ly = fmaf(m10, xc, fmaf(m11, yc, fmaf(m12, zc, m13 + cc)));
    float lz = fmaf(m20, xc, fmaf(m21, yc, fmaf(m22, zc, m23 + cc)));

    const float mx = 159.0f;
    lx = fminf(fmaxf(lx, 0.0f), mx);
    ly = fminf(fmaxf(ly, 0.0f), mx);
    lz = fminf(fmaxf(lz, 0.0f), mx);

    float fx0 = floorf(lx), fy0 = floorf(ly), fz0 = floorf(lz);
    float fx1 = fminf(fx0 + 1.0f, mx);
    float fy1 = fminf(fy0 + 1.0f, mx);
    float fz1 = fminf(fz0 + 1.0f, mx);

    int ix0 = (int)fx0, iy0 = (int)fy0, iz0 = (int)fz0;
    int ix1 = (int)fx1, iy1 = (int)fy1, iz1 = (int)fz1;

    // voxelmorph convention: w_lo = loc1 - loc (weight of LOWER corner)
    float wxl = fx1 - lx, wyl = fy1 - ly, wzl = fz1 - lz;
    float wxh = 1.0f - wxl, wyh = 1.0f - wyl, wzh = 1.0f - wzl;

    const float2* vb = (const float2*)(vol) + (size_t)b * VOX_PER_B;

    int r0 = ix0 * H, r1 = ix1 * H;
    int p00 = (r0 + iy0) * W, p01 = (r0 + iy1) * W;
    int p10 = (r1 + iy0) * W, p11 = (r1 + iy1) * W;

    float2 v000 = vb[p00 + iz0], v001 = vb[p00 + iz1];
    float2 v010 = vb[p01 + iz0], v011 = vb[p01 + iz1];
    float2 v100 = vb[p10 + iz0], v101 = vb[p10 + iz1];
    float2 v110 = vb[p11 + iz0], v111 = vb[p11 + iz1];

    float w000 = wxl * wyl * wzl, w001 = wxl * wyl * wzh;
    float w010 = wxl * wyh * wzl, w011 = wxl * wyh * wzh;
    float w100 = wxh * wyl * wzl, w101 = wxh * wyl * wzh;
    float w110 = wxh * wyh * wzl, w111 = wxh * wyh * wzh;

    float ox = v000.x * w000 + v001.x * w001 + v010.x * w010 + v011.x * w011
             + v100.x * w100 + v101.x * w101 + v110.x * w110 + v111.x * w111;
    float oy = v000.y * w000 + v001.y * w001 + v010.y * w010 + v011.y * w011
             + v100.y * w100 + v101.y * w101 + v110.y * w110 + v111.y * w111;

    float2 o; o.x = ox; o.y = oy;
    ((float2*)out)[tid] = o;
}

extern "C" void kernel_launch(void* const* d_in, const int* in_sizes, int n_in,
                              void* d_out, int out_size, void* d_ws, size_t ws_size,
                              hipStream_t stream) {
    const float* vol = (const float*)d_in[0];
    const float* trf = (const float*)d_in[1];
    float* out = (float*)d_out;

    st_affine_trilinear<<<NBLOCKS, 256, 0, stream>>>(vol, trf, out);
}

// Round 3
// 73.801 us; speedup vs baseline: 1.3676x; 1.3342x over previous
//
#include <hip/hip_runtime.h>

// SpatialTransformer: batched affine warp + trilinear resample.
// vol: [4,160,160,160,2] fp32, trf: [4,3,4] fp32 -> out: [4,160,160,160,2] fp32.
// Sample coord = M * (x - c) + t + c, c = (160-1)/2 = 79.5, clamped to [0,159].
//
// r2: XCD chunked swizzle (FETCH 252.7->48.9 MB) but dur ~flat -> gather-issue bound.
// r3: pair the two z-corners of each (ix,iy) row into ONE 16B load (they are
//     provably adjacent: base = min(iz0,158), iz1 == base+1 always; iz0==159
//     case selects the high half for the lower corner, whose weight is 0).
//     8 gathers -> 4 gathers per voxel. + factorized trilinear + NT stores.

constexpr int D = 160, H = 160, W = 160, C = 2;
constexpr unsigned VOX_PER_B = D * H * W;          // 4,096,000
constexpr unsigned TOTAL = 4u * VOX_PER_B;         // 16,384,000
constexpr unsigned NBLOCKS = TOTAL / 256u;         // 64,000 (exact)
constexpr unsigned NXCD = 8;
constexpr unsigned CHUNK = NBLOCKS / NXCD;         // 8,000

struct VPair { float2 lo, hi; };  // 16B: voxels [zb] and [zb+1] of one row

__global__ __launch_bounds__(256) void st_affine_trilinear(
    const float* __restrict__ vol,
    const float* __restrict__ trf,
    float* __restrict__ out)
{
    // bijective chunked XCD swizzle: each XCD gets a contiguous output slab.
    unsigned bid = blockIdx.x;
    unsigned swz = (bid & (NXCD - 1)) * CHUNK + (bid >> 3);
    unsigned tid = swz * 256u + threadIdx.x;

    // decompose: tid -> (b, i, j, k); consecutive tid walks k (coalesced).
    unsigned k = tid % (unsigned)W;
    unsigned t = tid / (unsigned)W;
    unsigned j = t % (unsigned)H;
    t /= (unsigned)H;
    unsigned i = t % (unsigned)D;
    unsigned b = t / (unsigned)D;

    // affine row-major [3][4]; b is wave-uniform (VOX_PER_B % 64 == 0)
    const float* m = trf + b * 12u;
    float m00 = m[0], m01 = m[1], m02 = m[2],  m03 = m[3];
    float m10 = m[4], m11 = m[5], m12 = m[6],  m13 = m[7];
    float m20 = m[8], m21 = m[9], m22 = m[10], m23 = m[11];

    const float cc = 79.5f;
    float xc = (float)i - cc, yc = (float)j - cc, zc = (float)k - cc;

    float lx = fmaf(m00, xc, fmaf(m01, yc, fmaf(m02, zc, m03 + cc)));
    float ly = fmaf(m10, xc, fmaf(m11, yc, fmaf(m12, zc, m13 + cc)));
    float lz = fmaf(m20, xc, fmaf(m21, yc, fmaf(m22, zc, m23 + cc)));

    const float mx = 159.0f;
    lx = fminf(fmaxf(lx, 0.0f), mx);
    ly = fminf(fmaxf(ly, 0.0f), mx);
    lz = fminf(fmaxf(lz, 0.0f), mx);

    float fx0 = floorf(lx), fy0 = floorf(ly), fz0 = floorf(lz);
    float fx1 = fminf(fx0 + 1.0f, mx);
    float fy1 = fminf(fy0 + 1.0f, mx);
    float fz1 = fminf(fz0 + 1.0f, mx);

    int ix0 = (int)fx0, iy0 = (int)fy0, iz0 = (int)fz0;
    int ix1 = (int)fx1, iy1 = (int)fy1;

    // voxelmorph convention: w_lo = loc1 - loc (weight of LOWER corner)
    float wxl = fx1 - lx, wyl = fy1 - ly, wzl = fz1 - lz;
    float wyh = 1.0f - wyl, wzh = 1.0f - wzl;
    float wxh = 1.0f - wxl;

    const float2* vb = (const float2*)(vol) + (size_t)b * VOX_PER_B;

    // z-pair base: iz1 == zb+1 always (incl. clamp case iz0==159 -> zb=158,
    // where v_lo must take the HIGH half; its weight wzl is exactly 0 there).
    int zb = min(iz0, W - 2);
    bool sel_hi = (iz0 != zb);

    int r0 = ix0 * H, r1 = ix1 * H;
    int p00 = (r0 + iy0) * W + zb, p01 = (r0 + iy1) * W + zb;
    int p10 = (r1 + iy0) * W + zb, p11 = (r1 + iy1) * W + zb;

    VPair q00 = *(const VPair*)(vb + p00);
    VPair q01 = *(const VPair*)(vb + p01);
    VPair q10 = *(const VPair*)(vb + p10);
    VPair q11 = *(const VPair*)(vb + p11);

    float2 a00 = sel_hi ? q00.hi : q00.lo;
    float2 a01 = sel_hi ? q01.hi : q01.lo;
    float2 a10 = sel_hi ? q10.hi : q10.lo;
    float2 a11 = sel_hi ? q11.hi : q11.lo;

    // factorized trilinear: z -> y -> x (exact: wzh = 1-wzl etc.)
    float zx00 = a00.x * wzl + q00.hi.x * wzh, zy00 = a00.y * wzl + q00.hi.y * wzh;
    float zx01 = a01.x * wzl + q01.hi.x * wzh, zy01 = a01.y * wzl + q01.hi.y * wzh;
    float zx10 = a10.x * wzl + q10.hi.x * wzh, zy10 = a10.y * wzl + q10.hi.y * wzh;
    float zx11 = a11.x * wzl + q11.hi.x * wzh, zy11 = a11.y * wzl + q11.hi.y * wzh;

    float yx0 = zx00 * wyl + zx01 * wyh, yy0 = zy00 * wyl + zy01 * wyh;
    float yx1 = zx10 * wyl + zx11 * wyh, yy1 = zy10 * wyl + zy11 * wyh;

    float ox = yx0 * wxl + yx1 * wxh;
    float oy = yy0 * wxl + yy1 * wxh;

    // non-temporal streaming store: keep the 131 MB output out of L2/L3
    // so vol stays cache-resident.
    float2 o; o.x = ox; o.y = oy;
    double od;
    __builtin_memcpy(&od, &o, 8);
    __builtin_nontemporal_store(od, (double*)out + tid);
}

extern "C" void kernel_launch(void* const* d_in, const int* in_sizes, int n_in,
                              void* d_out, int out_size, void* d_ws, size_t ws_size,
                              hipStream_t stream) {
    const float* vol = (const float*)d_in[0];
    const float* trf = (const float*)d_in[1];
    float* out = (float*)d_out;

    st_affine_trilinear<<<NBLOCKS, 256, 0, stream>>>(vol, trf, out);
}